// Round 1
// baseline (120.132 us; speedup 1.0000x reference)
//
#include <hip/hip_runtime.h>

// GNNComm: edge-MLP mean aggregation over all ordered pairs.
// N=2048 nodes, COMM_DIM=8, HIDDEN=64.
//
// Math: out[i,d] = (sum_{j!=i} relu(X1[i]+X2[j]+b1) @ W2^T)[d] / (N-1) + b2[d]
// with X1 = msg @ W1[:, :8]^T, X2 = msg @ W1[:, 8:]^T.
//
// Trick: relu(z) = (z+|z|)/2  =>
//   S[i,h] = sum_{all j} relu(a_ih + x_jh)
//          = 0.5*(N*a_ih + SX_h + sum_j |a_ih + x_jh|),  a = X1[i]+b1, x = X2[j]
// Then subtract the j==i diagonal D[i,h] = relu(a_ih + x_ih).
// Inner loop is 2 VALU ops/pair (add + add-with-abs-modifier) -> ~7us VALU floor.

#define NN 2048
#define HH 64
#define DD 8

#define ITILES 32     // i-tiles (64 i's each)
#define JCHUNKS 16    // j-chunks (128 j's each)
#define JCHUNK (NN / JCHUNKS)

// --- K1: A[i,h] = X1[i,h] + b1[h];  X2[i,h] ---
__global__ void prep_kernel(const float* __restrict__ msg,
                            const float* __restrict__ W1,
                            const float* __restrict__ b1,
                            float* __restrict__ A,
                            float* __restrict__ X2) {
    int idx = blockIdx.x * blockDim.x + threadIdx.x;  // 0 .. N*H-1
    int i = idx >> 6;
    int h = idx & 63;
    const float* m = msg + i * DD;
    const float* w = W1 + h * (2 * DD);
    float x1 = 0.f, x2 = 0.f;
#pragma unroll
    for (int d = 0; d < 8; ++d) {
        float mv = m[d];
        x1 += mv * w[d];
        x2 += mv * w[8 + d];
    }
    A[idx]  = x1 + b1[h];
    X2[idx] = x2;
}

// --- K2: pairwise |a+x| accumulation, partials over j-chunks ---
// Block covers 64 i's x all 64 h for one j-chunk of 128 j's.
// Thread: hq = tid&15 -> h in [4*hq, 4*hq+4); il = tid>>4 -> i in [i0+4*il, i0+4*il+4).
// Each thread: 4x4 accumulators, reuses the float4 x-load across 4 i's.
__global__ void __launch_bounds__(256) pair_kernel(const float* __restrict__ A,
                                                   const float* __restrict__ X2,
                                                   float* __restrict__ C,
                                                   float* __restrict__ SX) {
    int it = blockIdx.x & (ITILES - 1);   // i-tile 0..31
    int jc = blockIdx.x >> 5;             // j-chunk 0..15
    int hq = threadIdx.x & 15;
    int il = threadIdx.x >> 4;            // 0..15
    int h0 = hq * 4;
    int i0 = it * 64 + il * 4;

    float a[4][4];
#pragma unroll
    for (int k = 0; k < 4; ++k)
#pragma unroll
        for (int hh = 0; hh < 4; ++hh)
            a[k][hh] = A[(i0 + k) * HH + h0 + hh];

    float acc[4][4];
#pragma unroll
    for (int k = 0; k < 4; ++k)
#pragma unroll
        for (int hh = 0; hh < 4; ++hh)
            acc[k][hh] = 0.f;
    float accx0 = 0.f, accx1 = 0.f, accx2 = 0.f, accx3 = 0.f;

    const float4* X2v = (const float4*)X2;  // row j = 16 float4's
    int j0 = jc * JCHUNK;
#pragma unroll 2
    for (int j = j0; j < j0 + JCHUNK; ++j) {
        float4 x = X2v[j * 16 + hq];
        accx0 += x.x; accx1 += x.y; accx2 += x.z; accx3 += x.w;
#pragma unroll
        for (int k = 0; k < 4; ++k) {
            acc[k][0] += __builtin_fabsf(a[k][0] + x.x);
            acc[k][1] += __builtin_fabsf(a[k][1] + x.y);
            acc[k][2] += __builtin_fabsf(a[k][2] + x.z);
            acc[k][3] += __builtin_fabsf(a[k][3] + x.w);
        }
    }

    // partial |.|-sums -> C (16-way atomic contention per address, cheap)
#pragma unroll
    for (int k = 0; k < 4; ++k)
#pragma unroll
        for (int hh = 0; hh < 4; ++hh)
            atomicAdd(&C[(i0 + k) * HH + h0 + hh], acc[k][hh]);

    // SX partial: one copy per j-chunk (only the it==0, il==0 threads add)
    if (it == 0 && il == 0) {
        atomicAdd(&SX[h0 + 0], accx0);
        atomicAdd(&SX[h0 + 1], accx1);
        atomicAdd(&SX[h0 + 2], accx2);
        atomicAdd(&SX[h0 + 3], accx3);
    }
}

// --- K3: combine: S = 0.5*(N*a + SX + C), subtract diagonal, @W2^T, scale, +b2 ---
__global__ void out_kernel(const float* __restrict__ A,
                           const float* __restrict__ X2,
                           const float* __restrict__ C,
                           const float* __restrict__ SX,
                           const float* __restrict__ W2,
                           const float* __restrict__ b2,
                           float* __restrict__ out) {
    int idx = blockIdx.x * blockDim.x + threadIdx.x;  // 0 .. N*DD-1
    int i = idx >> 3;
    int d = idx & 7;
    float s = 0.f;
#pragma unroll 8
    for (int h = 0; h < HH; ++h) {
        float a = A[i * HH + h];
        float S = 0.5f * ((float)NN * a + SX[h] + C[i * HH + h]);
        float t = a + X2[i * HH + h];
        float diag = t > 0.f ? t : 0.f;
        s += (S - diag) * W2[d * HH + h];
    }
    out[idx] = s * (1.0f / (float)(NN - 1)) + b2[d];
}

extern "C" void kernel_launch(void* const* d_in, const int* in_sizes, int n_in,
                              void* d_out, int out_size, void* d_ws, size_t ws_size,
                              hipStream_t stream) {
    const float* msg = (const float*)d_in[0];  // [N, 8]
    const float* W1  = (const float*)d_in[1];  // [64, 16]
    const float* b1  = (const float*)d_in[2];  // [64]
    const float* W2  = (const float*)d_in[3];  // [8, 64]
    const float* b2  = (const float*)d_in[4];  // [8]
    float* out = (float*)d_out;                // [N, 8]

    float* ws = (float*)d_ws;
    float* A  = ws;                // N*H
    float* X2 = ws + NN * HH;      // N*H
    float* C  = ws + 2 * NN * HH;  // N*H  (|.|-sum partials)
    float* SX = ws + 3 * NN * HH;  // H

    // zero the accumulation buffers (ws is poisoned 0xAA before every call)
    hipMemsetAsync(C, 0, (NN * HH + HH) * sizeof(float), stream);

    prep_kernel<<<(NN * HH) / 256, 256, 0, stream>>>(msg, W1, b1, A, X2);
    pair_kernel<<<ITILES * JCHUNKS, 256, 0, stream>>>(A, X2, C, SX);
    out_kernel<<<(NN * DD) / 256, 256, 0, stream>>>(A, X2, C, SX, W2, b2, out);
}

// Round 2
// 85.980 us; speedup vs baseline: 1.3972x; 1.3972x over previous
//
#include <hip/hip_runtime.h>

// GNNComm: out[i,:] = mean_{j!=i} relu(concat(m_i,m_j)@W1^T + b1) @ W2^T + b2
// N=2048, D=8, H=64.
//
// relu(z) = (z+|z|)/2  =>
//   S[i,h] = sum_j relu(a_ih + x_jh) = 0.5*(N*a_ih + SX_h + C_ih),
//   C_ih = sum_j |a_ih + x_jh|,  a = X1[i]+b1, x = X2[j], SX = sum_j x
// out = ( (S - diag) @ W2^T ) / (N-1) + b2,  diag = relu(a + x_i).
//
// R1 post-mortem: C accumulated via 2M global fp32 atomics -> 32MB HBM
// write-through traffic == the kernel duration. This version: per-block
// W2-projection epilogue in LDS + plain stores of P[jc][i][d] partials
// (2MB), X2 chunk staged in LDS so the hot loop is pure VALU.

#define NN 2048
#define HH 64
#define DD 8

#define ITILES 32          // 32 i-tiles x 64 i
#define JCHUNKS 32         // 32 j-chunks x 64 j
#define JCHUNK (NN / JCHUNKS)

// --- K1: A[i,h] = X1[i,h]+b1[h]; X2[i,h]; zero SX ---
__global__ void prep_kernel(const float* __restrict__ msg,
                            const float* __restrict__ W1,
                            const float* __restrict__ b1,
                            float* __restrict__ A,
                            float* __restrict__ X2,
                            float* __restrict__ SX) {
    int idx = blockIdx.x * blockDim.x + threadIdx.x;  // 0 .. N*H-1
    if (blockIdx.x == 0 && threadIdx.x < HH) SX[threadIdx.x] = 0.f;
    int i = idx >> 6;
    int h = idx & 63;
    const float4* m4 = (const float4*)(msg + i * DD);
    const float4* w4 = (const float4*)(W1 + h * (2 * DD));
    float4 m0 = m4[0], m1 = m4[1];
    float4 w0 = w4[0], w1 = w4[1], w2 = w4[2], w3 = w4[3];
    float x1 = m0.x * w0.x + m0.y * w0.y + m0.z * w0.z + m0.w * w0.w
             + m1.x * w1.x + m1.y * w1.y + m1.z * w1.z + m1.w * w1.w;
    float x2 = m0.x * w2.x + m0.y * w2.y + m0.z * w2.z + m0.w * w2.w
             + m1.x * w3.x + m1.y * w3.y + m1.z * w3.z + m1.w * w3.w;
    A[idx]  = x1 + b1[h];
    X2[idx] = x2;
}

// --- K2: pairwise |a+x| + in-block W2 projection -> P[jc][i][d] partials ---
// Block (it,jc): 64 i x 64 h x 64 j. Thread: hq=tid&15 (4 h's), il=tid>>4 (4 i's).
__global__ void __launch_bounds__(256, 4)
pair_kernel(const float* __restrict__ A,
            const float* __restrict__ X2,
            const float* __restrict__ W2,
            float* __restrict__ P,
            float* __restrict__ SX) {
    __shared__ float4 sX2[JCHUNK * 16];   // staged chunk: [64 j][16 hq] = 16KB
    __shared__ float  T[64][68];          // |.|-sum tile, padded (17.4KB)

    int it = blockIdx.x & (ITILES - 1);
    int jc = blockIdx.x >> 5;
    int hq = threadIdx.x & 15;
    int il = threadIdx.x >> 4;
    int h0 = hq * 4;
    int i0 = it * 64 + il * 4;

    // stage X2 chunk (plain coalesced float4 loads)
    {
        const float4* X2v = (const float4*)X2 + jc * JCHUNK * 16;
#pragma unroll
        for (int r = 0; r < 4; ++r) {
            int t = threadIdx.x + r * 256;
            sX2[t] = X2v[t];
        }
    }

    float a[4][4];
#pragma unroll
    for (int k = 0; k < 4; ++k) {
        float4 av = *(const float4*)&A[(i0 + k) * HH + h0];
        a[k][0] = av.x; a[k][1] = av.y; a[k][2] = av.z; a[k][3] = av.w;
    }
    float acc[4][4];
#pragma unroll
    for (int k = 0; k < 4; ++k)
#pragma unroll
        for (int hh = 0; hh < 4; ++hh)
            acc[k][hh] = 0.f;

    __syncthreads();

#pragma unroll 4
    for (int j = 0; j < JCHUNK; ++j) {
        float4 x = sX2[j * 16 + hq];
#pragma unroll
        for (int k = 0; k < 4; ++k) {
            acc[k][0] += __builtin_fabsf(a[k][0] + x.x);
            acc[k][1] += __builtin_fabsf(a[k][1] + x.y);
            acc[k][2] += __builtin_fabsf(a[k][2] + x.z);
            acc[k][3] += __builtin_fabsf(a[k][3] + x.w);
        }
    }

    // SX partials: one block column (it==0) re-reads the staged chunk
    if (it == 0 && il == 0) {
        float4 s = make_float4(0.f, 0.f, 0.f, 0.f);
        for (int j = 0; j < JCHUNK; ++j) {
            float4 x = sX2[j * 16 + hq];
            s.x += x.x; s.y += x.y; s.z += x.z; s.w += x.w;
        }
        atomicAdd(&SX[h0 + 0], s.x);
        atomicAdd(&SX[h0 + 1], s.y);
        atomicAdd(&SX[h0 + 2], s.z);
        atomicAdd(&SX[h0 + 3], s.w);
    }

    // write |.|-tile to LDS
#pragma unroll
    for (int k = 0; k < 4; ++k)
        *(float4*)&T[il * 4 + k][h0] =
            make_float4(acc[k][0], acc[k][1], acc[k][2], acc[k][3]);
    __syncthreads();

    // project onto W2: thread -> (iL, d) and (iL+32, d); P unscaled sum_h C*W2
    {
        int iL = threadIdx.x >> 3;        // 0..31
        int d  = threadIdx.x & 7;
        const float4* w2v = (const float4*)W2;  // [8][16]
        float s0 = 0.f, s1 = 0.f;
#pragma unroll
        for (int hb = 0; hb < 16; ++hb) {
            float4 w = w2v[d * 16 + hb];
            float4 t0 = *(const float4*)&T[iL][hb * 4];
            float4 t1 = *(const float4*)&T[iL + 32][hb * 4];
            s0 += t0.x * w.x + t0.y * w.y + t0.z * w.z + t0.w * w.w;
            s1 += t1.x * w.x + t1.y * w.y + t1.z * w.z + t1.w * w.w;
        }
        int ibase = it * 64;
        P[(jc * NN + ibase + iL) * DD + d]      = s0;
        P[(jc * NN + ibase + iL + 32) * DD + d] = s1;
    }
}

// --- K3: one wave per i: out[i,d] = (0.5*sum_jc P + sum_h v_h W2[d,h])/(N-1)+b2 ---
// v_h = 0.5*(N*a + SX_h) - relu(a + x2_i)
__global__ void out_kernel(const float* __restrict__ A,
                           const float* __restrict__ X2,
                           const float* __restrict__ P,
                           const float* __restrict__ SX,
                           const float* __restrict__ W2,
                           const float* __restrict__ b2,
                           float* __restrict__ out) {
    int i = blockIdx.x * 4 + (threadIdx.x >> 6);
    int l = threadIdx.x & 63;

    float a  = A[i * HH + l];
    float x2 = X2[i * HH + l];
    float sx = SX[l];
    float v = 0.5f * ((float)NN * a + sx);
    float t = a + x2;
    v -= (t > 0.f ? t : 0.f);

    float p0 = v * W2[0 * HH + l];
    float p1 = v * W2[1 * HH + l];
    float p2 = v * W2[2 * HH + l];
    float p3 = v * W2[3 * HH + l];
    float p4 = v * W2[4 * HH + l];
    float p5 = v * W2[5 * HH + l];
    float p6 = v * W2[6 * HH + l];
    float p7 = v * W2[7 * HH + l];
#pragma unroll
    for (int m = 1; m < 64; m <<= 1) {
        p0 += __shfl_xor(p0, m);
        p1 += __shfl_xor(p1, m);
        p2 += __shfl_xor(p2, m);
        p3 += __shfl_xor(p3, m);
        p4 += __shfl_xor(p4, m);
        p5 += __shfl_xor(p5, m);
        p6 += __shfl_xor(p6, m);
        p7 += __shfl_xor(p7, m);
    }

    // sum P over 32 jc's: lane (d = l&7, g = l>>3) takes jc = r*8+g
    int d = l & 7, g = l >> 3;
    float q = 0.f;
#pragma unroll
    for (int r = 0; r < 4; ++r)
        q += P[((r * 8 + g) * NN + i) * DD + d];
    q += __shfl_xor(q, 8);
    q += __shfl_xor(q, 16);
    q += __shfl_xor(q, 32);

    if (l < 8) {
        float pv = p0;
        pv = (l == 1) ? p1 : pv;
        pv = (l == 2) ? p2 : pv;
        pv = (l == 3) ? p3 : pv;
        pv = (l == 4) ? p4 : pv;
        pv = (l == 5) ? p5 : pv;
        pv = (l == 6) ? p6 : pv;
        pv = (l == 7) ? p7 : pv;
        out[i * DD + l] = (0.5f * q + pv) * (1.0f / (float)(NN - 1)) + b2[l];
    }
}

extern "C" void kernel_launch(void* const* d_in, const int* in_sizes, int n_in,
                              void* d_out, int out_size, void* d_ws, size_t ws_size,
                              hipStream_t stream) {
    const float* msg = (const float*)d_in[0];  // [N, 8]
    const float* W1  = (const float*)d_in[1];  // [64, 16]
    const float* b1  = (const float*)d_in[2];  // [64]
    const float* W2  = (const float*)d_in[3];  // [8, 64]
    const float* b2  = (const float*)d_in[4];  // [8]
    float* out = (float*)d_out;                // [N, 8]

    float* ws = (float*)d_ws;
    float* A  = ws;                       // N*H
    float* X2 = ws + NN * HH;             // N*H
    float* P  = ws + 2 * NN * HH;         // JCHUNKS*N*DD = 512K floats
    float* SX = P + JCHUNKS * NN * DD;    // H

    prep_kernel<<<(NN * HH) / 256, 256, 0, stream>>>(msg, W1, b1, A, X2, SX);
    pair_kernel<<<ITILES * JCHUNKS, 256, 0, stream>>>(A, X2, W2, P, SX);
    out_kernel<<<NN / 4, 256, 0, stream>>>(A, X2, P, SX, W2, b2, out);
}

// Round 3
// 82.734 us; speedup vs baseline: 1.4520x; 1.0392x over previous
//
#include <hip/hip_runtime.h>

// GNNComm: out[i,:] = mean_{j!=i} relu(concat(m_i,m_j)@W1^T + b1) @ W2^T + b2
// N=2048, D=8, H=64.
//
// relu(z) = (z+|z|)/2 =>
//   S[i,h] = sum_j relu(a_ih + x_jh) = 0.5*(N*a_ih + SX_h + C_ih),
//   C_ih = sum_j |a_ih + x_jh|, a = X1[i]+b1, x = X2[j], SX = sum_j x_jh
// out[i,d] = 0.5*sum_h (C_ih + SX_h + N*a_ih - 2*relu(a_ih+x_ih)) W2[d,h]
//            / (N-1) + b2[d]
//
// R2 post-mortem: timed window is dominated by the harness's 40us/268MB
// 0xAA ws-poison fill (untouchable). Controllable cost = my 3 dispatches
// + P partial round-trip. This version fuses everything into 2 dispatches:
// each (it,jc) block atomicAdds its W2-projected tile contribution into
// out directly (512K atomics ~ 8MB, vs R1's 32MB lesson); the SX term is
// distributed per-chunk (block-local sSX), and the diagonal blocks
// (jc==it) add the N*a - 2*relu(diag) + b2 terms.

#define NN 2048
#define HH 64
#define DD 8

#define ITILES 32          // 32 i-tiles x 64 i
#define JCHUNKS 32         // 32 j-chunks x 64 j
#define JCHUNK (NN / JCHUNKS)
#define INV_SCALE (0.5f / (float)(NN - 1))

// --- K1: A[i,h] = X1[i,h]+b1[h]; X2[i,h]; zero out ---
__global__ void prep_kernel(const float* __restrict__ msg,
                            const float* __restrict__ W1,
                            const float* __restrict__ b1,
                            float* __restrict__ A,
                            float* __restrict__ X2,
                            float* __restrict__ out) {
    int idx = blockIdx.x * blockDim.x + threadIdx.x;  // 0 .. N*H-1
    if (idx < NN * DD) out[idx] = 0.f;                // zero the atomic target
    int i = idx >> 6;
    int h = idx & 63;
    const float4* m4 = (const float4*)(msg + i * DD);
    const float4* w4 = (const float4*)(W1 + h * (2 * DD));
    float4 m0 = m4[0], m1 = m4[1];
    float4 w0 = w4[0], w1 = w4[1], w2 = w4[2], w3 = w4[3];
    float x1 = m0.x * w0.x + m0.y * w0.y + m0.z * w0.z + m0.w * w0.w
             + m1.x * w1.x + m1.y * w1.y + m1.z * w1.z + m1.w * w1.w;
    float x2 = m0.x * w2.x + m0.y * w2.y + m0.z * w2.z + m0.w * w2.w
             + m1.x * w3.x + m1.y * w3.y + m1.z * w3.z + m1.w * w3.w;
    A[idx]  = x1 + b1[h];
    X2[idx] = x2;
}

// --- K2: pairwise |a+x| + W2 projection + direct atomic scatter to out ---
// Block (it,jc): 64 i x 64 h x 64 j. Thread: hq=tid&15 (4 h's), il=tid>>4 (4 i's).
__global__ void __launch_bounds__(256, 4)
pair_fused(const float* __restrict__ A,
           const float* __restrict__ X2,
           const float* __restrict__ W2,
           const float* __restrict__ b2,
           float* __restrict__ out) {
    __shared__ float4 sX2[JCHUNK * 16];   // staged chunk: [64 j][16 hq] = 16KB
    __shared__ float  T[64][68];          // per-block tile, padded
    __shared__ float4 sSXv[16];           // chunk column-sums of X2

    int it = blockIdx.x & (ITILES - 1);
    int jc = blockIdx.x >> 5;
    int hq = threadIdx.x & 15;
    int il = threadIdx.x >> 4;
    int h0 = hq * 4;
    int i0 = it * 64 + il * 4;
    bool des = (jc == it);                // diagonal block: owns per-i terms

    // stage X2 chunk (coalesced float4 loads)
    {
        const float4* X2v = (const float4*)X2 + jc * JCHUNK * 16;
#pragma unroll
        for (int r = 0; r < 4; ++r) {
            int t = threadIdx.x + r * 256;
            sX2[t] = X2v[t];
        }
    }

    float a[4][4];
#pragma unroll
    for (int k = 0; k < 4; ++k) {
        float4 av = *(const float4*)&A[(i0 + k) * HH + h0];
        a[k][0] = av.x; a[k][1] = av.y; a[k][2] = av.z; a[k][3] = av.w;
    }
    float acc[4][4];
#pragma unroll
    for (int k = 0; k < 4; ++k)
#pragma unroll
        for (int hh = 0; hh < 4; ++hh)
            acc[k][hh] = 0.f;

    __syncthreads();

#pragma unroll 4
    for (int j = 0; j < JCHUNK; ++j) {
        float4 x = sX2[j * 16 + hq];
#pragma unroll
        for (int k = 0; k < 4; ++k) {
            acc[k][0] += __builtin_fabsf(a[k][0] + x.x);
            acc[k][1] += __builtin_fabsf(a[k][1] + x.y);
            acc[k][2] += __builtin_fabsf(a[k][2] + x.z);
            acc[k][3] += __builtin_fabsf(a[k][3] + x.w);
        }
    }

    const float* sX2f = (const float*)sX2;

    // chunk column-sums (wave-0 tail loop; stall hidden by 4 blocks/CU)
    if (threadIdx.x < 64) {
        float s0 = 0.f, s1 = 0.f, s2 = 0.f, s3 = 0.f;
#pragma unroll 8
        for (int j = 0; j < JCHUNK; j += 4) {
            s0 += sX2f[(j + 0) * 64 + threadIdx.x];
            s1 += sX2f[(j + 1) * 64 + threadIdx.x];
            s2 += sX2f[(j + 2) * 64 + threadIdx.x];
            s3 += sX2f[(j + 3) * 64 + threadIdx.x];
        }
        ((float*)sSXv)[threadIdx.x] = (s0 + s1) + (s2 + s3);
    }

    // write tile to LDS; diagonal block folds in N*a - 2*relu(a + x_i)
#pragma unroll
    for (int k = 0; k < 4; ++k) {
        float t0 = acc[k][0], t1 = acc[k][1], t2 = acc[k][2], t3 = acc[k][3];
        if (des) {
            int jl = il * 4 + k;  // local j index == local i index on diagonal
            float z0 = a[k][0] + sX2f[jl * 64 + h0 + 0];
            float z1 = a[k][1] + sX2f[jl * 64 + h0 + 1];
            float z2 = a[k][2] + sX2f[jl * 64 + h0 + 2];
            float z3 = a[k][3] + sX2f[jl * 64 + h0 + 3];
            t0 += (float)NN * a[k][0] - 2.f * (z0 > 0.f ? z0 : 0.f);
            t1 += (float)NN * a[k][1] - 2.f * (z1 > 0.f ? z1 : 0.f);
            t2 += (float)NN * a[k][2] - 2.f * (z2 > 0.f ? z2 : 0.f);
            t3 += (float)NN * a[k][3] - 2.f * (z3 > 0.f ? z3 : 0.f);
        }
        *(float4*)&T[il * 4 + k][h0] = make_float4(t0, t1, t2, t3);
    }
    __syncthreads();

    // project (T + sSX) onto W2 rows -> atomicAdd into out
    {
        int iL = threadIdx.x >> 3;        // 0..31
        int d  = threadIdx.x & 7;
        const float4* w2v = (const float4*)W2;  // [8][16]
        float s0 = 0.f, s1 = 0.f, c = 0.f;
#pragma unroll
        for (int hb = 0; hb < 16; ++hb) {
            float4 w  = w2v[d * 16 + hb];
            float4 t0 = *(const float4*)&T[iL][hb * 4];
            float4 t1 = *(const float4*)&T[iL + 32][hb * 4];
            float4 sx = sSXv[hb];
            s0 += t0.x * w.x + t0.y * w.y + t0.z * w.z + t0.w * w.w;
            s1 += t1.x * w.x + t1.y * w.y + t1.z * w.z + t1.w * w.w;
            c  += sx.x * w.x + sx.y * w.y + sx.z * w.z + sx.w * w.w;
        }
        float v0 = (s0 + c) * INV_SCALE;
        float v1 = (s1 + c) * INV_SCALE;
        if (des) {
            float bv = b2[d];
            v0 += bv;
            v1 += bv;
        }
        int ibase = it * 64;
        atomicAdd(&out[(ibase + iL) * DD + d], v0);
        atomicAdd(&out[(ibase + iL + 32) * DD + d], v1);
    }
}

extern "C" void kernel_launch(void* const* d_in, const int* in_sizes, int n_in,
                              void* d_out, int out_size, void* d_ws, size_t ws_size,
                              hipStream_t stream) {
    const float* msg = (const float*)d_in[0];  // [N, 8]
    const float* W1  = (const float*)d_in[1];  // [64, 16]
    const float* b1  = (const float*)d_in[2];  // [64]
    const float* W2  = (const float*)d_in[3];  // [8, 64]
    const float* b2  = (const float*)d_in[4];  // [8]
    float* out = (float*)d_out;                // [N, 8]

    float* ws = (float*)d_ws;
    float* A  = ws;            // N*H
    float* X2 = ws + NN * HH;  // N*H

    prep_kernel<<<(NN * HH) / 256, 256, 0, stream>>>(msg, W1, b1, A, X2, out);
    pair_fused<<<ITILES * JCHUNKS, 256, 0, stream>>>(A, X2, W2, b2, out);
}